// Round 9
// baseline (328.945 us; speedup 1.0000x reference)
//
#include <hip/hip_runtime.h>

#define EPS_BN 1e-5f
#define BINSHIFT 9
#define BINW 512
#define P_EPB 8192   // edges per block in count/scatter passes
#define LDS_CAP 10240
#define NREP 32      // stat-accumulator replicas (atomic de-contention)

typedef __attribute__((ext_vector_type(8))) short short8;
typedef __attribute__((ext_vector_type(4))) float f32x4;

__device__ __forceinline__ unsigned short f2bf(float x) {
    unsigned int u = __float_as_uint(x);
    u += 0x7fffu + ((u >> 16) & 1u);
    return (unsigned short)(u >> 16);
}
__device__ __forceinline__ float bf2f(unsigned short h) {
    return __uint_as_float(((unsigned int)h) << 16);
}
__device__ __forceinline__ float bflo(unsigned u) { return __uint_as_float(u << 16); }
__device__ __forceinline__ float bfhi(unsigned u) { return __uint_as_float(u & 0xffff0000u); }

// dequant-accumulate 4 int8 cols from one u32
__device__ __forceinline__ void acc4(unsigned u, float sc, float& a0, float& a1,
                                     float& a2, float& a3) {
    a0 += sc * (float)(signed char)(u & 0xff);
    a1 += sc * (float)(signed char)((u >> 8) & 0xff);
    a2 += sc * (float)(signed char)((u >> 16) & 0xff);
    a3 += sc * (float)(signed char)(u >> 24);
}

// inclusive scans (all threads of the block must enter)
__device__ __forceinline__ void scan512(int* a, int t) {
    for (int off = 1; off < 512; off <<= 1) {
        int v = (t >= off) ? a[t - off] : 0;
        __syncthreads();
        a[t] += v;
        __syncthreads();
    }
}
__device__ __forceinline__ void scan256(int* a, int t) {
    for (int off = 1; off < 256; off <<= 1) {
        int v = (t >= off) ? a[t - off] : 0;
        __syncthreads();
        a[t] += v;
        __syncthreads();
    }
}

// ------------------------------------------------ prep: cvt_w | p1_count
__global__ __launch_bounds__(256) void prep_kernel(
    const float* __restrict__ Ws1, const float* __restrict__ Wn1,
    const float* __restrict__ Ws2, const float* __restrict__ Wn2,
    unsigned short* __restrict__ W1f, unsigned short* __restrict__ W2f,
    const int* __restrict__ dst, int* __restrict__ counts, int E, int NB, int wB) {
    int tid = threadIdx.x;
    if (blockIdx.x < wB) {
        int i = blockIdx.x * 256 + tid;
        if (i < 128 * 256) {  // W1: MT=256, NCT=16
            int j = i & 7, L = (i >> 3) & 63, c = (i >> 9) & 15, kk = i >> 13;
            int k = kk * 32 + (L >> 4) * 8 + j;
            int col = c * 16 + (L & 15);
            float v = (col < 128) ? Ws1[k * 128 + col] : Wn1[k * 128 + (col - 128)];
            W1f[i] = f2bf(v);
        } else {
            int idx = i - 128 * 256;
            if (idx < 128 * 128) {  // W2: MT=128, NCT=8
                int j = idx & 7, L = (idx >> 3) & 63, c = (idx >> 9) & 7, kk = idx >> 12;
                int k = kk * 32 + (L >> 4) * 8 + j;
                int col = c * 16 + (L & 15);
                float v = (col < 64) ? Ws2[k * 64 + col] : Wn2[k * 64 + (col - 64)];
                W2f[idx] = f2bf(v);
            }
        }
    } else {
        __shared__ int hist[512];
        int blk = blockIdx.x - wB;
        int e0 = blk * P_EPB, e1 = min(e0 + P_EPB, E);
        for (int b = tid; b < 512; b += 256) hist[b] = 0;
        __syncthreads();
        for (int e = e0 + tid; e < e1; e += 256) atomicAdd(&hist[dst[e] >> BINSHIFT], 1);
        __syncthreads();
        for (int b = tid; b < NB; b += 256) counts[blk * NB + b] = hist[b];
    }
}

// ------------------------------------------------ p2a: per-bin scan over edge-blocks
__global__ __launch_bounds__(256) void p2a(const int* __restrict__ counts,
                                           int* __restrict__ segrel,
                                           int* __restrict__ tot, int NB, int NBLK) {
    __shared__ int s[256];
    int b = blockIdx.x, t = threadIdx.x;
    int v = (t < NBLK) ? counts[t * NB + b] : 0;
    s[t] = v;
    __syncthreads();
    scan256(s, t);
    if (t < NBLK) segrel[t * NB + b] = s[t] - v;
    if (t == 255) tot[b] = s[255];
}

// ------------------------------------------------ p3: direct binned scatter
__global__ __launch_bounds__(512) void p3_scatter(const int* __restrict__ src,
                                                  const int* __restrict__ dst,
                                                  const int* __restrict__ segrel,
                                                  const int* __restrict__ tot,
                                                  unsigned* __restrict__ epack,
                                                  int E, int NB) {
    __shared__ int cur[512];
    int t = threadIdx.x;
    int blk = blockIdx.x;
    int e0 = blk * P_EPB, e1 = min(e0 + P_EPB, E);
    int tv = (t < NB) ? tot[t] : 0;
    cur[t] = tv;
    __syncthreads();
    scan512(cur, t);
    int base = cur[t] - tv;  // exclusive bin base
    __syncthreads();
    cur[t] = (t < NB) ? (base + segrel[blk * NB + t]) : 0;
    __syncthreads();
    for (int e = e0 + t; e < e1; e += 512) {
        int d = dst[e];
        int pos = atomicAdd(&cur[d >> BINSHIFT], 1);
        epack[pos] = ((unsigned)src[e] << BINSHIFT) | ((unsigned)d & (BINW - 1));
    }
}

// ------------------------------------------------ p4: per-bin CSR finalize
__global__ __launch_bounds__(512) void p4_csr(const unsigned* __restrict__ epack,
                                              const int* __restrict__ tot,
                                              int* __restrict__ row_start,
                                              int* __restrict__ cntg,
                                              float* __restrict__ inv_deg,
                                              int* __restrict__ csr_src, int N, int NB) {
    __shared__ int ncnt[512];
    __shared__ int cursor[512];
    __shared__ int bb[512];
    __shared__ int lsrc[LDS_CAP];
    int t = threadIdx.x;
    int b = blockIdx.x;
    int tv = (t < NB) ? tot[t] : 0;
    bb[t] = tv;
    __syncthreads();
    scan512(bb, t);
    int e1 = bb[b];           // inclusive: end of bin b
    int e0 = bb[b] - tot[b];  // exclusive: start of bin b
    int m = e1 - e0;
    int nbase = b << BINSHIFT;
    int nn = min(N - nbase, BINW);
    ncnt[t] = 0;
    __syncthreads();
    for (int i = e0 + t; i < e1; i += 512)
        atomicAdd(&ncnt[epack[i] & (BINW - 1)], 1);
    __syncthreads();
    int c = ncnt[t];
    scan512(ncnt, t);
    int excl = ncnt[t] - c;
    if (t < nn) {
        int node = nbase + t;
        row_start[node] = e0 + excl;
        cntg[node] = c;
        inv_deg[node] = 1.0f / fmaxf((float)c, 1.0f);
    }
    cursor[t] = excl;
    __syncthreads();
    for (int i = e0 + t; i < e1; i += 512) {
        unsigned v = epack[i];
        int pos = atomicAdd(&cursor[v & (BINW - 1)], 1);
        if (pos < LDS_CAP) lsrc[pos] = (int)(v >> BINSHIFT);
    }
    __syncthreads();
    int mm = min(m, LDS_CAP);
    for (int i = t; i < mm; i += 512) csr_src[e0 + i] = lsrc[i];
}

// ---------------------------------------------------------------- dual GEMM (MFMA bf16)
template <int MT, int MSELF, bool SELFBF, bool FUSEBN, bool AFP32>
__global__ __launch_bounds__(256) void gemm_dual(const unsigned short* __restrict__ Ab,
                                                 const float* __restrict__ Af,
                                                 const unsigned short* __restrict__ Wf,
                                                 float* __restrict__ YselfF,
                                                 unsigned short* __restrict__ YselfB,
                                                 signed char* __restrict__ Ynb8,
                                                 float* __restrict__ scl, int N,
                                                 const float* __restrict__ sums,
                                                 const float* __restrict__ gamma,
                                                 const float* __restrict__ beta,
                                                 float invN) {
    constexpr int K = 128;
    constexpr int NCT = MT / 16;
    constexpr int NCTW = NCT / 2;  // col-tiles per wave
    constexpr int KS = K / 32;
    constexpr int MNB = MT - MSELF;
    constexpr int APADF = 132;  // fp32 A-tile row stride (floats)
    constexpr int APADH = 136;  // bf16 A-tile row stride (shorts)
    static_assert(MSELF * 2 == MT, "col-half split requires MSELF == MT/2");
    __shared__ float ssc[128], ssh[128];
    __shared__ __align__(16) char AsRaw[AFP32 ? (64 * APADF * 4) : (64 * APADH * 2)];

    if constexpr (FUSEBN) {
        if (threadIdx.x < 128) {
            int c = threadIdx.x;
            float su = 0.f, sq = 0.f;
            for (int r = 0; r < NREP; r++) {
                su += sums[r * 256 + c];
                sq += sums[r * 256 + 128 + c];
            }
            float mu = su * invN;
            float var = sq * invN - mu * mu;
            float sc = gamma[c] * rsqrtf(var + EPS_BN);
            ssc[c] = sc;
            ssh[c] = beta[c] - mu * sc;
        }
    }

    // ---- stage A tile (coalesced)
    int row0g = blockIdx.x * 64;
    if (AFP32) {
        float* As = (float*)AsRaw;
        for (int i = threadIdx.x; i < 64 * 32; i += 256) {  // 2048 f32x4
            int r = i >> 5, cv = i & 31;
            int gr = row0g + r;
            if (gr >= N) gr = N - 1;
            *(f32x4*)&As[r * APADF + cv * 4] = *(const f32x4*)&Af[(size_t)gr * K + cv * 4];
        }
    } else {
        unsigned short* As = (unsigned short*)AsRaw;
        for (int i = threadIdx.x; i < 64 * 16; i += 256) {  // 1024 short8
            int r = i >> 4, cv = i & 15;
            int gr = row0g + r;
            if (gr >= N) gr = N - 1;
            *(short8*)&As[r * APADH + cv * 8] = *(const short8*)&Ab[(size_t)gr * K + cv * 8];
        }
    }
    __syncthreads();

    int wv = threadIdx.x >> 6, lane = threadIdx.x & 63;
    int ch = wv & 1;   // 0 = self cols, 1 = neighbor cols
    int rt = wv >> 1;  // row-tile within block
    int row0 = row0g + rt * 32;
    int m = lane & 15, quad = lane >> 4;

    short8 afrag[2][KS];
#pragma unroll
    for (int t = 0; t < 2; t++) {
        int lr = rt * 32 + t * 16 + m;  // local row in tile
#pragma unroll
        for (int kk = 0; kk < KS; kk++) {
            short8 raw;
            if (AFP32) {
                const float* ap = ((const float*)AsRaw) + lr * APADF + quad * 8 + kk * 32;
                f32x4 a = *(const f32x4*)ap;
                f32x4 b = *(const f32x4*)(ap + 4);
#pragma unroll
                for (int j = 0; j < 4; j++) {
                    raw[j] = (short)f2bf(a[j]);
                    raw[4 + j] = (short)f2bf(b[j]);
                }
            } else {
                raw = *(const short8*)(((const unsigned short*)AsRaw) + lr * APADH +
                                       quad * 8 + kk * 32);
            }
            if (FUSEBN) {
#pragma unroll
                for (int j = 0; j < 8; j++) {
                    int c = kk * 32 + quad * 8 + j;
                    float f = bf2f((unsigned short)raw[j]) * ssc[c] + ssh[c];
                    raw[j] = (short)f2bf(fmaxf(f, 0.f));
                }
            }
            afrag[t][kk] = raw;
        }
    }

    f32x4 acc[2][NCTW];
#pragma unroll
    for (int t = 0; t < 2; t++)
        for (int ci = 0; ci < NCTW; ci++)
            for (int j = 0; j < 4; j++) acc[t][ci][j] = 0.f;

    const short8* Bf = (const short8*)Wf;
    int cbase = ch * NCTW;
#pragma unroll
    for (int kk = 0; kk < KS; kk++) {
#pragma unroll
        for (int ci = 0; ci < NCTW; ci++) {
            short8 bfrag = Bf[(kk * NCT + cbase + ci) * 64 + lane];
#pragma unroll
            for (int t = 0; t < 2; t++)
                acc[t][ci] = __builtin_amdgcn_mfma_f32_16x16x32_bf16(afrag[t][kk], bfrag,
                                                                     acc[t][ci], 0, 0, 0);
        }
    }

    // C/D layout: col = lane&15, row = quad*4 + reg
    if (ch == 0) {
#pragma unroll
        for (int t = 0; t < 2; t++) {
#pragma unroll
            for (int ci = 0; ci < NCTW; ci++) {
                int colg = ci * 16 + m;
#pragma unroll
                for (int r = 0; r < 4; r++) {
                    int row = row0 + t * 16 + quad * 4 + r;
                    if (row < N) {
                        float v = acc[t][ci][r];
                        if (SELFBF)
                            YselfB[(size_t)row * MSELF + colg] = f2bf(v);
                        else
                            YselfF[(size_t)row * MSELF + colg] = v;
                    }
                }
            }
        }
    } else {
#pragma unroll
        for (int t = 0; t < 2; t++) {
#pragma unroll
            for (int r = 0; r < 4; r++) {
                float mx = 0.f;
#pragma unroll
                for (int ci = 0; ci < NCTW; ci++) mx = fmaxf(mx, fabsf(acc[t][ci][r]));
#pragma unroll
                for (int off = 1; off < 16; off <<= 1) mx = fmaxf(mx, __shfl_xor(mx, off));
                int row = row0 + t * 16 + quad * 4 + r;
                float qs = 127.0f / fmaxf(mx, 1e-30f);
                if (row < N) {
                    if (m == 0) scl[row] = mx * (1.0f / 127.0f);
#pragma unroll
                    for (int ci = 0; ci < NCTW; ci++) {
                        int colg = ci * 16 + m;
                        int q = __float2int_rn(acc[t][ci][r] * qs);
                        Ynb8[(size_t)row * MNB + colg] = (signed char)q;
                    }
                }
            }
        }
    }
}

// ------------------------------------------------- aggregation + fused BN stats
// Layer 1: one wave per node (persistent, static interleave). int8 rows (128B)
// PAIR-GATHERED: each u32 lane-load holds 4 cols; wave halves cover 2 edges
// per VMEM instruction (1 req / 2 edges; lines/edge unchanged). Scales via
// uniform s_load + select (SMEM pipe). Accumulate 4 cols/lane (a0..a3);
// per-node epilogue combines halves (shfl_xor 32) and redistributes to the
// 2-col/lane output layout via 4 shfl + selects.
__global__ __launch_bounds__(256) void agg_row128(const unsigned int* __restrict__ Sb,
                                                  const unsigned int* __restrict__ Tq32,
                                                  const float* __restrict__ scl,
                                                  const int* __restrict__ row_start,
                                                  const int* __restrict__ cnt,
                                                  const float* __restrict__ inv_deg,
                                                  const int* __restrict__ csr_src,
                                                  const float* __restrict__ bias,
                                                  unsigned int* __restrict__ Out,
                                                  float* __restrict__ sums,
                                                  int N, int totalWaves) {
    int wv = threadIdx.x >> 6, lane = threadIdx.x & 63;
    int g = lane >> 5, h = lane & 31;  // half, intra-half u32 index
    int c = lane * 2;
    float bs0 = bias[c], bs1 = bias[c + 1];
    float S0 = 0.f, S1 = 0.f, Q0 = 0.f, Q1 = 0.f;

    int n = blockIdx.x * 4 + wv;
    int pStart = 0, pEc = 0, pIv = 0;
    float pInv = 0.f;
    if (n < N) {
        pStart = row_start[n];
        pEc = cnt[n];
        pInv = inv_deg[n];
        if (pEc > 0) pIv = csr_src[pStart + min(lane, min(pEc, 64) - 1)];
    }
    for (; n < N; n += totalWaves) {
        int start = pStart, ec = pEc, iv = pIv;
        float inv = pInv;
        unsigned su = Sb[(size_t)n * 64 + lane];  // in flight across edge loop
        int n2 = n + totalWaves;
        if (n2 < N) {
            pStart = row_start[n2];
            pEc = cnt[n2];
            pInv = inv_deg[n2];
            if (pEc > 0) pIv = csr_src[pStart + min(lane, min(pEc, 64) - 1)];
        }
        float a0 = 0.f, a1 = 0.f, a2 = 0.f, a3 = 0.f;
        for (int base = 0; base < ec; base += 64) {
            int ecc = min(ec - base, 64);
            if (base) iv = csr_src[start + base + min(lane, ecc - 1)];
            int e = 0;
            for (; e + 16 <= ecc; e += 16) {  // 8 pair-gathers = 16 edges
                unsigned u[8];
                float sc[8];
#pragma unroll
                for (int j = 0; j < 8; j++) {
                    int s0 = __builtin_amdgcn_readlane(iv, e + 2 * j);
                    int s1 = __builtin_amdgcn_readlane(iv, e + 2 * j + 1);
                    int sg = g ? s1 : s0;
                    u[j] = Tq32[(size_t)sg * 32 + h];
                    float c0 = scl[s0], c1 = scl[s1];
                    sc[j] = g ? c1 : c0;
                }
#pragma unroll
                for (int j = 0; j < 8; j++) acc4(u[j], sc[j], a0, a1, a2, a3);
            }
            if (e + 8 <= ecc) {  // 4 pair-gathers = 8 edges
                unsigned u[4];
                float sc[4];
#pragma unroll
                for (int j = 0; j < 4; j++) {
                    int s0 = __builtin_amdgcn_readlane(iv, e + 2 * j);
                    int s1 = __builtin_amdgcn_readlane(iv, e + 2 * j + 1);
                    int sg = g ? s1 : s0;
                    u[j] = Tq32[(size_t)sg * 32 + h];
                    float c0 = scl[s0], c1 = scl[s1];
                    sc[j] = g ? c1 : c0;
                }
#pragma unroll
                for (int j = 0; j < 4; j++) acc4(u[j], sc[j], a0, a1, a2, a3);
                e += 8;
            }
            if (e < ecc) {  // tail 1..7 edges: 4 clamped pairs, scale zeroed
                int r = ecc - e;
                unsigned u[4];
                float sc[4];
#pragma unroll
                for (int j = 0; j < 4; j++) {
                    int s0 = __builtin_amdgcn_readlane(iv, min(e + 2 * j, ecc - 1));
                    int s1 = __builtin_amdgcn_readlane(iv, min(e + 2 * j + 1, ecc - 1));
                    int sg = g ? s1 : s0;
                    u[j] = Tq32[(size_t)sg * 32 + h];  // clamped dups: L1 hits
                    float c0 = scl[s0], c1 = scl[s1];
                    float cg = g ? c1 : c0;
                    sc[j] = ((2 * j + g) < r) ? cg : 0.f;  // mask via scale
                }
#pragma unroll
                for (int j = 0; j < 4; j++) acc4(u[j], sc[j], a0, a1, a2, a3);
            }
        }
        // combine halves, then redistribute 4-col/lane -> 2-col/lane
        a0 += __shfl_xor(a0, 32);
        a1 += __shfl_xor(a1, 32);
        a2 += __shfl_xor(a2, 32);
        a3 += __shfl_xor(a3, 32);
        int hs = lane >> 1;  // source lane holding cols 4*hs..4*hs+3
        float v0 = __shfl(a0, hs), v1 = __shfl(a1, hs);
        float v2 = __shfl(a2, hs), v3 = __shfl(a3, hs);
        float aL0 = (lane & 1) ? v2 : v0;
        float aL1 = (lane & 1) ? v3 : v1;
        float h0 = bflo(su) + aL0 * inv + bs0;
        float h1 = bfhi(su) + aL1 * inv + bs1;
        Out[(size_t)n * 64 + lane] = (unsigned)f2bf(h0) | ((unsigned)f2bf(h1) << 16);
        S0 += h0; Q0 += h0 * h0;
        S1 += h1; Q1 += h1 * h1;
    }
    __shared__ float ls[256];
    ls[threadIdx.x] = 0.f;
    __syncthreads();
    atomicAdd(&ls[c], S0);
    atomicAdd(&ls[c + 1], S1);
    atomicAdd(&ls[128 + c], Q0);
    atomicAdd(&ls[129 + c], Q1);
    __syncthreads();
    float* dstS = sums + (size_t)(blockIdx.x & (NREP - 1)) * 256;
    atomicAdd(&dstS[threadIdx.x], ls[threadIdx.x]);
}

// Layer 2: one node per wave (persistent, static interleave). int8 rows (64B)
// QUAD-GATHERED: 16-lane quarters cover 4 edges per VMEM instruction. Scales
// via 4 uniform s_loads + selects. Accumulate 4 cols/lane (h = lane&15);
// epilogue combines quads (shfl_xor 16,32) and redistributes.
__global__ __launch_bounds__(256) void agg_row64(const unsigned int* __restrict__ Tq32,
                                                 const float* __restrict__ scl,
                                                 const int* __restrict__ row_start,
                                                 const int* __restrict__ cnt,
                                                 const float* __restrict__ inv_deg,
                                                 const int* __restrict__ csr_src,
                                                 const float* __restrict__ bias,
                                                 float* Self, float* __restrict__ sums,
                                                 int N, int totalWaves) {
    int wv = threadIdx.x >> 6, lane = threadIdx.x & 63;
    int g = lane >> 5;
    int h = lane & 15;            // intra-quarter u32 index
    int qq = (lane >> 4) & 3;     // quarter = edge slot within quad
    int hw = lane & 31;
    int c = hw * 2;
    float bs0 = bias[c], bs1 = bias[c + 1];
    float S0 = 0.f, S1 = 0.f, Q0 = 0.f, Q1 = 0.f;

    int n = blockIdx.x * 4 + wv;
    int pStart = 0, pEc = 0, pIv = 0;
    if (n < N) {
        pStart = row_start[n];
        pEc = cnt[n];
        if (pEc > 0) pIv = csr_src[pStart + min(lane, min(pEc, 64) - 1)];
    }
    for (; n < N; n += totalWaves) {
        int start = pStart, ec = pEc, iv = pIv;
        float inv = inv_deg[n];
        int n2 = n + totalWaves;
        if (n2 < N) {
            pStart = row_start[n2];
            pEc = cnt[n2];
            if (pEc > 0) pIv = csr_src[pStart + min(lane, min(pEc, 64) - 1)];
        }
        float a0 = 0.f, a1 = 0.f, a2 = 0.f, a3 = 0.f;
        for (int base = 0; base < ec; base += 64) {
            int ecc = min(ec - base, 64);
            if (base) iv = csr_src[start + base + min(lane, ecc - 1)];
            int e = 0;
            for (; e + 8 <= ecc; e += 8) {  // 2 quad-gathers = 8 edges
                unsigned u[2];
                float sc[2];
#pragma unroll
                for (int j = 0; j < 2; j++) {
                    int eb = e + 4 * j;
                    int sA = __builtin_amdgcn_readlane(iv, eb);
                    int sB = __builtin_amdgcn_readlane(iv, eb + 1);
                    int sC = __builtin_amdgcn_readlane(iv, eb + 2);
                    int sD = __builtin_amdgcn_readlane(iv, eb + 3);
                    int sLo = (lane & 16) ? sB : sA;
                    int sHi = (lane & 16) ? sD : sC;
                    int s = (lane & 32) ? sHi : sLo;
                    u[j] = Tq32[(size_t)s * 16 + h];
                    float cA = scl[sA], cB = scl[sB], cC = scl[sC], cD = scl[sD];
                    float cLo = (lane & 16) ? cB : cA;
                    float cHi = (lane & 16) ? cD : cC;
                    sc[j] = (lane & 32) ? cHi : cLo;
                }
#pragma unroll
                for (int j = 0; j < 2; j++) acc4(u[j], sc[j], a0, a1, a2, a3);
            }
            if (e < ecc) {  // tail 1..7 edges: 2 clamped quads, scale zeroed
                int r = ecc - e;
                unsigned u[2];
                float sc[2];
#pragma unroll
                for (int j = 0; j < 2; j++) {
                    int eb = e + 4 * j;
                    int sA = __builtin_amdgcn_readlane(iv, min(eb, ecc - 1));
                    int sB = __builtin_amdgcn_readlane(iv, min(eb + 1, ecc - 1));
                    int sC = __builtin_amdgcn_readlane(iv, min(eb + 2, ecc - 1));
                    int sD = __builtin_amdgcn_readlane(iv, min(eb + 3, ecc - 1));
                    int sLo = (lane & 16) ? sB : sA;
                    int sHi = (lane & 16) ? sD : sC;
                    int s = (lane & 32) ? sHi : sLo;
                    u[j] = Tq32[(size_t)s * 16 + h];
                    float cA = scl[sA], cB = scl[sB], cC = scl[sC], cD = scl[sD];
                    float cLo = (lane & 16) ? cB : cA;
                    float cHi = (lane & 16) ? cD : cC;
                    float cg = (lane & 32) ? cHi : cLo;
                    sc[j] = ((4 * j + qq) < r) ? cg : 0.f;
                }
#pragma unroll
                for (int j = 0; j < 2; j++) acc4(u[j], sc[j], a0, a1, a2, a3);
            }
        }
        // combine quads, then redistribute 4-col/lane -> 2-col/lane
        a0 += __shfl_xor(a0, 16);
        a1 += __shfl_xor(a1, 16);
        a2 += __shfl_xor(a2, 16);
        a3 += __shfl_xor(a3, 16);
        a0 += __shfl_xor(a0, 32);
        a1 += __shfl_xor(a1, 32);
        a2 += __shfl_xor(a2, 32);
        a3 += __shfl_xor(a3, 32);
        int hs = hw >> 1;  // source lane holding cols 4*hs..4*hs+3
        float v0 = __shfl(a0, hs), v1 = __shfl(a1, hs);
        float v2 = __shfl(a2, hs), v3 = __shfl(a3, hs);
        float aL0 = (lane & 1) ? v2 : v0;
        float aL1 = (lane & 1) ? v3 : v1;
        if (g == 0) {
            size_t off = (size_t)n * 64 + c;
            float h0 = Self[off] + aL0 * inv + bs0;
            float h1 = Self[off + 1] + aL1 * inv + bs1;
            Self[off] = h0;
            Self[off + 1] = h1;
            S0 += h0; Q0 += h0 * h0;
            S1 += h1; Q1 += h1 * h1;
        }
    }
    __shared__ float ls[128];
    if (threadIdx.x < 128) ls[threadIdx.x] = 0.f;
    __syncthreads();
    if (g == 0) {
        atomicAdd(&ls[c], S0);
        atomicAdd(&ls[c + 1], S1);
        atomicAdd(&ls[64 + c], Q0);
        atomicAdd(&ls[65 + c], Q1);
    }
    __syncthreads();
    if (threadIdx.x < 128) {
        float* dstS = sums + (size_t)(blockIdx.x & (NREP - 1)) * 128;
        atomicAdd(&dstS[threadIdx.x], ls[threadIdx.x]);
    }
}

// layer-2 apply (finalize folded, NREP-replicated sums): fp32 in-place, no ReLU
__global__ __launch_bounds__(256) void bn_apply_f64(float* H, const float* __restrict__ sums,
                                                    const float* __restrict__ gamma,
                                                    const float* __restrict__ beta,
                                                    int N, float invN) {
    __shared__ float ss[128];
    int tid = threadIdx.x;
    if (tid < 64) {
        float su = 0.f, sq = 0.f;
        for (int r = 0; r < NREP; r++) {
            su += sums[r * 128 + tid];
            sq += sums[r * 128 + 64 + tid];
        }
        float mu = su * invN;
        float var = sq * invN - mu * mu;
        float sc = gamma[tid] * rsqrtf(var + EPS_BN);
        ss[tid] = sc;
        ss[64 + tid] = beta[tid] - mu * sc;
    }
    __syncthreads();
    int total4 = N * 16;
    float4* H4 = (float4*)H;
    for (int i = blockIdx.x * 256 + threadIdx.x; i < total4; i += 256 * gridDim.x) {
        int c0 = (i * 4) & 63;
        float4 v = H4[i];
        float4 sc = *(const float4*)&ss[c0];
        float4 sh = *(const float4*)&ss[64 + c0];
        v.x = v.x * sc.x + sh.x;
        v.y = v.y * sc.y + sh.y;
        v.z = v.z * sc.z + sh.z;
        v.w = v.w * sc.w + sh.w;
        H4[i] = v;
    }
}

// ---------------------------------------------------------------- launch
extern "C" void kernel_launch(void* const* d_in, const int* in_sizes, int n_in,
                              void* d_out, int out_size, void* d_ws, size_t ws_size,
                              hipStream_t stream) {
    const float* X = (const float*)d_in[0];
    const int* src = (const int*)d_in[1];
    const int* dst = (const int*)d_in[2];
    const float* Wself1 = (const float*)d_in[3];
    const float* Wneigh1 = (const float*)d_in[4];
    const float* b1 = (const float*)d_in[5];
    const float* g1 = (const float*)d_in[6];
    const float* be1 = (const float*)d_in[7];
    const float* Wself2 = (const float*)d_in[8];
    const float* Wneigh2 = (const float*)d_in[9];
    const float* b2 = (const float*)d_in[10];
    const float* g2 = (const float*)d_in[11];
    const float* be2 = (const float*)d_in[12];
    float* out = (float*)d_out;

    const int N = in_sizes[0] / 128;
    const int E = in_sizes[1];
    const int NB = (N + BINW - 1) >> BINSHIFT;    // 196
    const int NBLK = (E + P_EPB - 1) / P_EPB;     // 196 (<=256 required by p2a)

    char* p = (char*)d_ws;
    auto carve = [&](size_t bytes) {
        char* r = p;
        p += (bytes + 255) & ~(size_t)255;
        return r;
    };
    float* sums1 = (float*)carve((size_t)NREP * 256 * 4);
    float* sums2 = (float*)carve((size_t)NREP * 128 * 4);
    size_t zero_bytes = (size_t)(p - (char*)d_ws);
    int* counts = (int*)carve((size_t)NBLK * NB * 4);
    int* segrel = (int*)carve((size_t)NBLK * NB * 4);
    int* tot = (int*)carve((size_t)NB * 4);
    unsigned* epack = (unsigned*)carve((size_t)E * 4);
    int* csr_src = (int*)carve((size_t)E * 4);
    int* row_start = (int*)carve((size_t)N * 4);
    int* cntg = (int*)carve((size_t)N * 4);
    float* inv_deg = (float*)carve((size_t)N * 4);
    unsigned short* W1f = (unsigned short*)carve(128 * 256 * 2);
    unsigned short* W2f = (unsigned short*)carve(128 * 128 * 2);
    unsigned short* bufS = (unsigned short*)carve((size_t)N * 128 * 2);  // self1 bf16
    signed char* Tq1 = (signed char*)carve((size_t)N * 128);  // neigh1 int8 (128B rows)
    float* scl1 = (float*)carve((size_t)N * 4);               // per-row scales
    signed char* Tq2 = (signed char*)carve((size_t)N * 64);   // neigh2 int8 (64B rows)
    float* scl2 = (float*)carve((size_t)N * 4);
    unsigned short* h1b = (unsigned short*)carve((size_t)N * 128 * 2);   // h1 pre-BN bf16

    hipMemsetAsync(d_ws, 0, zero_bytes, stream);

    const int wB = 192;
    const float invN = 1.0f / (float)N;
    prep_kernel<<<wB + NBLK, 256, 0, stream>>>(Wself1, Wneigh1, Wself2, Wneigh2, W1f, W2f,
                                               dst, counts, E, NB, wB);
    p2a<<<NB, 256, 0, stream>>>(counts, segrel, tot, NB, NBLK);
    p3_scatter<<<NBLK, 512, 0, stream>>>(src, dst, segrel, tot, epack, E, NB);
    p4_csr<<<NB, 512, 0, stream>>>(epack, tot, row_start, cntg, inv_deg, csr_src, N, NB);

    int ggrid = (N + 63) / 64;
    // ---- layer 1 (128 -> 128): fp32 X in (inline cvt), self bf16, neigh int8
    gemm_dual<256, 128, true, false, true><<<ggrid, 256, 0, stream>>>(
        nullptr, X, W1f, nullptr, bufS, Tq1, scl1, N, nullptr, nullptr, nullptr, 0.f);
    agg_row128<<<2048, 256, 0, stream>>>(
        (const unsigned int*)bufS, (const unsigned int*)Tq1, scl1, row_start, cntg,
        inv_deg, csr_src, b1, (unsigned int*)h1b, sums1, N, 8192);

    // ---- layer 2 (128 -> 64): BN1+ReLU fused into A-load; self fp32 -> out
    gemm_dual<128, 64, false, true, false><<<ggrid, 256, 0, stream>>>(
        h1b, nullptr, W2f, out, nullptr, Tq2, scl2, N, sums1, g1, be1, invN);
    agg_row64<<<2048, 256, 0, stream>>>(
        (const unsigned int*)Tq2, scl2, row_start, cntg, inv_deg, csr_src, b2, out,
        sums2, N, 8192);
    bn_apply_f64<<<2048, 256, 0, stream>>>(out, sums2, g2, be2, N, invN);
}

// Round 10
// 314.630 us; speedup vs baseline: 1.0455x; 1.0455x over previous
//
#include <hip/hip_runtime.h>

#define EPS_BN 1e-5f
#define BINSHIFT 9
#define BINW 512
#define P_EPB 8192   // edges per block in count/scatter passes
#define LDS_CAP 10240
#define NREP 32      // stat-accumulator replicas (atomic de-contention)

typedef __attribute__((ext_vector_type(8))) short short8;
typedef __attribute__((ext_vector_type(4))) float f32x4;

__device__ __forceinline__ unsigned short f2bf(float x) {
    unsigned int u = __float_as_uint(x);
    u += 0x7fffu + ((u >> 16) & 1u);
    return (unsigned short)(u >> 16);
}
__device__ __forceinline__ float bf2f(unsigned short h) {
    return __uint_as_float(((unsigned int)h) << 16);
}
__device__ __forceinline__ float bflo(unsigned u) { return __uint_as_float(u << 16); }
__device__ __forceinline__ float bfhi(unsigned u) { return __uint_as_float(u & 0xffff0000u); }
// int8 pair unpack from a u16 load
__device__ __forceinline__ float i8lo(unsigned short u) { return (float)(signed char)(u & 0xff); }
__device__ __forceinline__ float i8hi(unsigned short u) { return (float)(signed char)(u >> 8); }

// inclusive scans (all threads of the block must enter)
__device__ __forceinline__ void scan512(int* a, int t) {
    for (int off = 1; off < 512; off <<= 1) {
        int v = (t >= off) ? a[t - off] : 0;
        __syncthreads();
        a[t] += v;
        __syncthreads();
    }
}
__device__ __forceinline__ void scan256(int* a, int t) {
    for (int off = 1; off < 256; off <<= 1) {
        int v = (t >= off) ? a[t - off] : 0;
        __syncthreads();
        a[t] += v;
        __syncthreads();
    }
}

// ------------------------------------------------ prep: cvt_w | p1_count
__global__ __launch_bounds__(256) void prep_kernel(
    const float* __restrict__ Ws1, const float* __restrict__ Wn1,
    const float* __restrict__ Ws2, const float* __restrict__ Wn2,
    unsigned short* __restrict__ W1f, unsigned short* __restrict__ W2f,
    const int* __restrict__ dst, int* __restrict__ counts, int E, int NB, int wB) {
    int tid = threadIdx.x;
    if (blockIdx.x < wB) {
        int i = blockIdx.x * 256 + tid;
        if (i < 128 * 256) {  // W1: MT=256, NCT=16
            int j = i & 7, L = (i >> 3) & 63, c = (i >> 9) & 15, kk = i >> 13;
            int k = kk * 32 + (L >> 4) * 8 + j;
            int col = c * 16 + (L & 15);
            float v = (col < 128) ? Ws1[k * 128 + col] : Wn1[k * 128 + (col - 128)];
            W1f[i] = f2bf(v);
        } else {
            int idx = i - 128 * 256;
            if (idx < 128 * 128) {  // W2: MT=128, NCT=8
                int j = idx & 7, L = (idx >> 3) & 63, c = (idx >> 9) & 7, kk = idx >> 12;
                int k = kk * 32 + (L >> 4) * 8 + j;
                int col = c * 16 + (L & 15);
                float v = (col < 64) ? Ws2[k * 64 + col] : Wn2[k * 64 + (col - 64)];
                W2f[idx] = f2bf(v);
            }
        }
    } else {
        __shared__ int hist[512];
        int blk = blockIdx.x - wB;
        int e0 = blk * P_EPB, e1 = min(e0 + P_EPB, E);
        for (int b = tid; b < 512; b += 256) hist[b] = 0;
        __syncthreads();
        for (int e = e0 + tid; e < e1; e += 256) atomicAdd(&hist[dst[e] >> BINSHIFT], 1);
        __syncthreads();
        for (int b = tid; b < NB; b += 256) counts[blk * NB + b] = hist[b];
    }
}

// ------------------------------------------------ p2a: per-bin scan over edge-blocks
__global__ __launch_bounds__(256) void p2a(const int* __restrict__ counts,
                                           int* __restrict__ segrel,
                                           int* __restrict__ tot, int NB, int NBLK) {
    __shared__ int s[256];
    int b = blockIdx.x, t = threadIdx.x;
    int v = (t < NBLK) ? counts[t * NB + b] : 0;
    s[t] = v;
    __syncthreads();
    scan256(s, t);
    if (t < NBLK) segrel[t * NB + b] = s[t] - v;
    if (t == 255) tot[b] = s[255];
}

// ------------------------------------------------ p3: direct binned scatter
// Final position computed per edge: bbase[bin] + segrel[blk][bin] + LDS cursor.
// No LDS staging, no binary search; L2 write-combining absorbs the 4B scatter.
__global__ __launch_bounds__(512) void p3_scatter(const int* __restrict__ src,
                                                  const int* __restrict__ dst,
                                                  const int* __restrict__ segrel,
                                                  const int* __restrict__ tot,
                                                  unsigned* __restrict__ epack,
                                                  int E, int NB) {
    __shared__ int cur[512];
    int t = threadIdx.x;
    int blk = blockIdx.x;
    int e0 = blk * P_EPB, e1 = min(e0 + P_EPB, E);
    int tv = (t < NB) ? tot[t] : 0;
    cur[t] = tv;
    __syncthreads();
    scan512(cur, t);
    int base = cur[t] - tv;  // exclusive bin base
    __syncthreads();
    cur[t] = (t < NB) ? (base + segrel[blk * NB + t]) : 0;
    __syncthreads();
    for (int e = e0 + t; e < e1; e += 512) {
        int d = dst[e];
        int pos = atomicAdd(&cur[d >> BINSHIFT], 1);
        epack[pos] = ((unsigned)src[e] << BINSHIFT) | ((unsigned)d & (BINW - 1));
    }
}

// ------------------------------------------------ p4: per-bin CSR finalize
__global__ __launch_bounds__(512) void p4_csr(const unsigned* __restrict__ epack,
                                              const int* __restrict__ tot,
                                              int* __restrict__ row_start,
                                              int* __restrict__ cntg,
                                              float* __restrict__ inv_deg,
                                              int* __restrict__ csr_src, int N, int NB) {
    __shared__ int ncnt[512];
    __shared__ int cursor[512];
    __shared__ int bb[512];
    __shared__ int lsrc[LDS_CAP];
    int t = threadIdx.x;
    int b = blockIdx.x;
    int tv = (t < NB) ? tot[t] : 0;
    bb[t] = tv;
    __syncthreads();
    scan512(bb, t);
    int e1 = bb[b];           // inclusive: end of bin b
    int e0 = bb[b] - tot[b];  // exclusive: start of bin b
    int m = e1 - e0;
    int nbase = b << BINSHIFT;
    int nn = min(N - nbase, BINW);
    ncnt[t] = 0;
    __syncthreads();
    for (int i = e0 + t; i < e1; i += 512)
        atomicAdd(&ncnt[epack[i] & (BINW - 1)], 1);
    __syncthreads();
    int c = ncnt[t];
    scan512(ncnt, t);
    int excl = ncnt[t] - c;
    if (t < nn) {
        int node = nbase + t;
        row_start[node] = e0 + excl;
        cntg[node] = c;
        inv_deg[node] = 1.0f / fmaxf((float)c, 1.0f);
    }
    cursor[t] = excl;
    __syncthreads();
    for (int i = e0 + t; i < e1; i += 512) {
        unsigned v = epack[i];
        int pos = atomicAdd(&cursor[v & (BINW - 1)], 1);
        if (pos < LDS_CAP) lsrc[pos] = (int)(v >> BINSHIFT);
    }
    __syncthreads();
    int mm = min(m, LDS_CAP);
    for (int i = t; i < mm; i += 512) csr_src[e0 + i] = lsrc[i];
}

// ---------------------------------------------------------------- dual GEMM (MFMA bf16)
// Y = A[N,128] @ Wcat[128,MT].  B fragments read directly from global (Wf is
// 32-64KB, L1/L2-resident, coalesced 16B/lane).  A tile (64 rows) staged in
// LDS with coalesced loads + padded rows (2-way-free bank pattern).
// 4 waves = 2 row-tiles x 2 col-halves per 64-row block. MSELF == MT/2:
//  col-half 0 -> self output: bf16 (SELFBF) or fp32, row-major
//  col-half 1 -> INT8 row-major Ynb8 + per-row scale scl (rowmax/127)
// FUSEBN: A = BN+ReLU on-the-fly; sums is NREP-replicated [NREP][256].
template <int MT, int MSELF, bool SELFBF, bool FUSEBN, bool AFP32>
__global__ __launch_bounds__(256) void gemm_dual(const unsigned short* __restrict__ Ab,
                                                 const float* __restrict__ Af,
                                                 const unsigned short* __restrict__ Wf,
                                                 float* __restrict__ YselfF,
                                                 unsigned short* __restrict__ YselfB,
                                                 signed char* __restrict__ Ynb8,
                                                 float* __restrict__ scl, int N,
                                                 const float* __restrict__ sums,
                                                 const float* __restrict__ gamma,
                                                 const float* __restrict__ beta,
                                                 float invN) {
    constexpr int K = 128;
    constexpr int NCT = MT / 16;
    constexpr int NCTW = NCT / 2;  // col-tiles per wave
    constexpr int KS = K / 32;
    constexpr int MNB = MT - MSELF;
    constexpr int APADF = 132;  // fp32 A-tile row stride (floats)
    constexpr int APADH = 136;  // bf16 A-tile row stride (shorts)
    static_assert(MSELF * 2 == MT, "col-half split requires MSELF == MT/2");
    __shared__ float ssc[128], ssh[128];
    __shared__ __align__(16) char AsRaw[AFP32 ? (64 * APADF * 4) : (64 * APADH * 2)];

    if constexpr (FUSEBN) {
        if (threadIdx.x < 128) {
            int c = threadIdx.x;
            float su = 0.f, sq = 0.f;
            for (int r = 0; r < NREP; r++) {
                su += sums[r * 256 + c];
                sq += sums[r * 256 + 128 + c];
            }
            float mu = su * invN;
            float var = sq * invN - mu * mu;
            float sc = gamma[c] * rsqrtf(var + EPS_BN);
            ssc[c] = sc;
            ssh[c] = beta[c] - mu * sc;
        }
    }

    // ---- stage A tile (coalesced)
    int row0g = blockIdx.x * 64;
    if (AFP32) {
        float* As = (float*)AsRaw;
        for (int i = threadIdx.x; i < 64 * 32; i += 256) {  // 2048 f32x4
            int r = i >> 5, cv = i & 31;
            int gr = row0g + r;
            if (gr >= N) gr = N - 1;
            *(f32x4*)&As[r * APADF + cv * 4] = *(const f32x4*)&Af[(size_t)gr * K + cv * 4];
        }
    } else {
        unsigned short* As = (unsigned short*)AsRaw;
        for (int i = threadIdx.x; i < 64 * 16; i += 256) {  // 1024 short8
            int r = i >> 4, cv = i & 15;
            int gr = row0g + r;
            if (gr >= N) gr = N - 1;
            *(short8*)&As[r * APADH + cv * 8] = *(const short8*)&Ab[(size_t)gr * K + cv * 8];
        }
    }
    __syncthreads();

    int wv = threadIdx.x >> 6, lane = threadIdx.x & 63;
    int ch = wv & 1;   // 0 = self cols, 1 = neighbor cols
    int rt = wv >> 1;  // row-tile within block
    int row0 = row0g + rt * 32;
    int m = lane & 15, quad = lane >> 4;

    short8 afrag[2][KS];
#pragma unroll
    for (int t = 0; t < 2; t++) {
        int lr = rt * 32 + t * 16 + m;  // local row in tile
#pragma unroll
        for (int kk = 0; kk < KS; kk++) {
            short8 raw;
            if (AFP32) {
                const float* ap = ((const float*)AsRaw) + lr * APADF + quad * 8 + kk * 32;
                f32x4 a = *(const f32x4*)ap;
                f32x4 b = *(const f32x4*)(ap + 4);
#pragma unroll
                for (int j = 0; j < 4; j++) {
                    raw[j] = (short)f2bf(a[j]);
                    raw[4 + j] = (short)f2bf(b[j]);
                }
            } else {
                raw = *(const short8*)(((const unsigned short*)AsRaw) + lr * APADH +
                                       quad * 8 + kk * 32);
            }
            if (FUSEBN) {
#pragma unroll
                for (int j = 0; j < 8; j++) {
                    int c = kk * 32 + quad * 8 + j;
                    float f = bf2f((unsigned short)raw[j]) * ssc[c] + ssh[c];
                    raw[j] = (short)f2bf(fmaxf(f, 0.f));
                }
            }
            afrag[t][kk] = raw;
        }
    }

    f32x4 acc[2][NCTW];
#pragma unroll
    for (int t = 0; t < 2; t++)
        for (int ci = 0; ci < NCTW; ci++)
            for (int j = 0; j < 4; j++) acc[t][ci][j] = 0.f;

    const short8* Bf = (const short8*)Wf;
    int cbase = ch * NCTW;
#pragma unroll
    for (int kk = 0; kk < KS; kk++) {
#pragma unroll
        for (int ci = 0; ci < NCTW; ci++) {
            short8 bfrag = Bf[(kk * NCT + cbase + ci) * 64 + lane];
#pragma unroll
            for (int t = 0; t < 2; t++)
                acc[t][ci] = __builtin_amdgcn_mfma_f32_16x16x32_bf16(afrag[t][kk], bfrag,
                                                                     acc[t][ci], 0, 0, 0);
        }
    }

    // C/D layout: col = lane&15, row = quad*4 + reg
    if (ch == 0) {
#pragma unroll
        for (int t = 0; t < 2; t++) {
#pragma unroll
            for (int ci = 0; ci < NCTW; ci++) {
                int colg = ci * 16 + m;
#pragma unroll
                for (int r = 0; r < 4; r++) {
                    int row = row0 + t * 16 + quad * 4 + r;
                    if (row < N) {
                        float v = acc[t][ci][r];
                        if (SELFBF)
                            YselfB[(size_t)row * MSELF + colg] = f2bf(v);
                        else
                            YselfF[(size_t)row * MSELF + colg] = v;
                    }
                }
            }
        }
    } else {
#pragma unroll
        for (int t = 0; t < 2; t++) {
#pragma unroll
            for (int r = 0; r < 4; r++) {
                float mx = 0.f;
#pragma unroll
                for (int ci = 0; ci < NCTW; ci++) mx = fmaxf(mx, fabsf(acc[t][ci][r]));
#pragma unroll
                for (int off = 1; off < 16; off <<= 1) mx = fmaxf(mx, __shfl_xor(mx, off));
                int row = row0 + t * 16 + quad * 4 + r;
                float qs = 127.0f / fmaxf(mx, 1e-30f);
                if (row < N) {
                    if (m == 0) scl[row] = mx * (1.0f / 127.0f);
#pragma unroll
                    for (int ci = 0; ci < NCTW; ci++) {
                        int colg = ci * 16 + m;
                        int q = __float2int_rn(acc[t][ci][r] * qs);
                        Ynb8[(size_t)row * MNB + colg] = (signed char)q;
                    }
                }
            }
        }
    }
}

// ------------------------------------------------- aggregation + fused BN stats
// Layer 1: one wave per node (persistent, static interleave); int8 rows (128B):
// 64 lanes x u16 = 2 cols/lane; dequant a += scale[src] * i8. Edge indices
// loaded 64-at-a-time lane-parallel, broadcast via readlane (SGPR bases);
// next node's meta + index vector prefetched.  (r4/r7-proven structure.)
// Grid oversubscribed 2x (4096 blocks): dispatcher backfills as blocks retire,
// halving the persistent-loop drain tail (r9: occupancy 60% at exact-fill).
__global__ __launch_bounds__(256) void agg_row128(const unsigned int* __restrict__ Sb,
                                                  const unsigned short* __restrict__ Tq,
                                                  const float* __restrict__ scl,
                                                  const int* __restrict__ row_start,
                                                  const int* __restrict__ cnt,
                                                  const float* __restrict__ inv_deg,
                                                  const int* __restrict__ csr_src,
                                                  const float* __restrict__ bias,
                                                  unsigned int* __restrict__ Out,
                                                  float* __restrict__ sums,
                                                  int N, int totalWaves) {
    int wv = threadIdx.x >> 6, lane = threadIdx.x & 63;
    int c = lane * 2;
    float bs0 = bias[c], bs1 = bias[c + 1];
    float S0 = 0.f, S1 = 0.f, Q0 = 0.f, Q1 = 0.f;

    int n = blockIdx.x * 4 + wv;
    int pStart = 0, pEc = 0, pIv = 0;
    float pInv = 0.f;
    if (n < N) {
        pStart = row_start[n];
        pEc = cnt[n];
        pInv = inv_deg[n];
        if (pEc > 0) pIv = csr_src[pStart + min(lane, min(pEc, 64) - 1)];
    }
    for (; n < N; n += totalWaves) {
        int start = pStart, ec = pEc, iv = pIv;
        float inv = pInv;
        unsigned su = Sb[(size_t)n * 64 + lane];  // in flight across edge loop
        int n2 = n + totalWaves;
        if (n2 < N) {
            pStart = row_start[n2];
            pEc = cnt[n2];
            pInv = inv_deg[n2];
            if (pEc > 0) pIv = csr_src[pStart + min(lane, min(pEc, 64) - 1)];
        }
        float a0 = 0.f, a1 = 0.f;
        for (int base = 0; base < ec; base += 64) {
            int ecc = min(ec - base, 64);
            if (base) iv = csr_src[start + base + min(lane, ecc - 1)];
            int e = 0;
            for (; e + 16 <= ecc; e += 16) {
                unsigned short u[16];
                float sc[16];
#pragma unroll
                for (int j = 0; j < 16; j++) {
                    int s = __builtin_amdgcn_readlane(iv, e + j);
                    u[j] = Tq[(size_t)s * 64 + lane];
                    sc[j] = scl[s];
                }
#pragma unroll
                for (int j = 0; j < 16; j++) {
                    a0 += sc[j] * i8lo(u[j]);
                    a1 += sc[j] * i8hi(u[j]);
                }
            }
            if (e + 8 <= ecc) {
                unsigned short u[8];
                float sc[8];
#pragma unroll
                for (int j = 0; j < 8; j++) {
                    int s = __builtin_amdgcn_readlane(iv, e + j);
                    u[j] = Tq[(size_t)s * 64 + lane];
                    sc[j] = scl[s];
                }
#pragma unroll
                for (int j = 0; j < 8; j++) {
                    a0 += sc[j] * i8lo(u[j]);
                    a1 += sc[j] * i8hi(u[j]);
                }
                e += 8;
            }
            if (e < ecc) {
                int r = ecc - e;  // 1..7
                unsigned short u[8];
                float sc[8];
#pragma unroll
                for (int j = 0; j < 8; j++) {
                    int s = __builtin_amdgcn_readlane(iv, min(e + j, ecc - 1));
                    u[j] = Tq[(size_t)s * 64 + lane];  // clamped dups: L1 hits
                    sc[j] = scl[s];
                }
#pragma unroll
                for (int j = 0; j < 8; j++) {
                    if (j < r) {
                        a0 += sc[j] * i8lo(u[j]);
                        a1 += sc[j] * i8hi(u[j]);
                    }
                }
            }
        }
        float h0 = bflo(su) + a0 * inv + bs0;
        float h1 = bfhi(su) + a1 * inv + bs1;
        Out[(size_t)n * 64 + lane] = (unsigned)f2bf(h0) | ((unsigned)f2bf(h1) << 16);
        S0 += h0; Q0 += h0 * h0;
        S1 += h1; Q1 += h1 * h1;
    }
    __shared__ float ls[256];
    ls[threadIdx.x] = 0.f;
    __syncthreads();
    atomicAdd(&ls[c], S0);
    atomicAdd(&ls[c + 1], S1);
    atomicAdd(&ls[128 + c], Q0);
    atomicAdd(&ls[129 + c], Q1);
    __syncthreads();
    float* dstS = sums + (size_t)(blockIdx.x & (NREP - 1)) * 256;
    atomicAdd(&dstS[threadIdx.x], ls[threadIdx.x]);
}

// Layer 2: one node per wave (persistent, static interleave); int8 rows
// (64B = 32 u16): each 64-lane load covers TWO edges (half-wave g reads edge
// e+g). Dequant with per-row scale. Cross-half combine via shfl_xor.
// Grid oversubscribed 2x (4096 blocks) like layer 1.
__global__ __launch_bounds__(256) void agg_row64(const unsigned short* __restrict__ Tq,
                                                 const float* __restrict__ scl,
                                                 const int* __restrict__ row_start,
                                                 const int* __restrict__ cnt,
                                                 const float* __restrict__ inv_deg,
                                                 const int* __restrict__ csr_src,
                                                 const float* __restrict__ bias,
                                                 float* Self, float* __restrict__ sums,
                                                 int N, int totalWaves) {
    int wv = threadIdx.x >> 6, lane = threadIdx.x & 63;
    int g = lane >> 5, h = lane & 31;
    int c = h * 2;
    float bs0 = bias[c], bs1 = bias[c + 1];
    float S0 = 0.f, S1 = 0.f, Q0 = 0.f, Q1 = 0.f;

    int n = blockIdx.x * 4 + wv;
    int pStart = 0, pEc = 0, pIv = 0;
    if (n < N) {
        pStart = row_start[n];
        pEc = cnt[n];
        if (pEc > 0) pIv = csr_src[pStart + min(lane, min(pEc, 64) - 1)];
    }
    for (; n < N; n += totalWaves) {
        int start = pStart, ec = pEc, iv = pIv;
        float inv = inv_deg[n];
        int n2 = n + totalWaves;
        if (n2 < N) {
            pStart = row_start[n2];
            pEc = cnt[n2];
            if (pEc > 0) pIv = csr_src[pStart + min(lane, min(pEc, 64) - 1)];
        }
        float a0 = 0.f, a1 = 0.f;
        for (int base = 0; base < ec; base += 64) {
            int ecc = min(ec - base, 64);
            if (base) iv = csr_src[start + base + min(lane, ecc - 1)];
            int e = 0;
            for (; e + 8 <= ecc; e += 8) {  // 8 edges = 4 pair-gathers
                unsigned short u[4];
                float sc[4];
#pragma unroll
                for (int j = 0; j < 4; j++) {
                    int s0 = __builtin_amdgcn_readlane(iv, e + 2 * j);
                    int s1 = __builtin_amdgcn_readlane(iv, e + 2 * j + 1);
                    int sg = g ? s1 : s0;
                    u[j] = Tq[(size_t)sg * 32 + h];
                    sc[j] = scl[sg];
                }
#pragma unroll
                for (int j = 0; j < 4; j++) {
                    a0 += sc[j] * i8lo(u[j]);
                    a1 += sc[j] * i8hi(u[j]);
                }
            }
            if (e < ecc) {
                int r = ecc - e;  // 1..7
                unsigned short u[4];
                float sc[4];
#pragma unroll
                for (int j = 0; j < 4; j++) {
                    int s0 = __builtin_amdgcn_readlane(iv, min(e + 2 * j, ecc - 1));
                    int s1 = __builtin_amdgcn_readlane(iv, min(e + 2 * j + 1, ecc - 1));
                    int sg = g ? s1 : s0;
                    u[j] = Tq[(size_t)sg * 32 + h];
                    sc[j] = scl[sg];
                }
#pragma unroll
                for (int j = 0; j < 4; j++) {
                    bool ok = (2 * j + g) < r;  // per-lane mask (g), uniform rest
                    a0 += ok ? sc[j] * i8lo(u[j]) : 0.f;
                    a1 += ok ? sc[j] * i8hi(u[j]) : 0.f;
                }
            }
        }
        // combine the two halves (each holds alternating-edge partials)
        a0 += __shfl_xor(a0, 32);
        a1 += __shfl_xor(a1, 32);
        if (g == 0) {
            size_t off = (size_t)n * 64 + c;
            float h0 = Self[off] + a0 * inv + bs0;
            float h1 = Self[off + 1] + a1 * inv + bs1;
            Self[off] = h0;
            Self[off + 1] = h1;
            S0 += h0; Q0 += h0 * h0;
            S1 += h1; Q1 += h1 * h1;
        }
    }
    __shared__ float ls[128];
    if (threadIdx.x < 128) ls[threadIdx.x] = 0.f;
    __syncthreads();
    if (g == 0) {
        atomicAdd(&ls[c], S0);
        atomicAdd(&ls[c + 1], S1);
        atomicAdd(&ls[64 + c], Q0);
        atomicAdd(&ls[65 + c], Q1);
    }
    __syncthreads();
    if (threadIdx.x < 128) {
        float* dstS = sums + (size_t)(blockIdx.x & (NREP - 1)) * 128;
        atomicAdd(&dstS[threadIdx.x], ls[threadIdx.x]);
    }
}

// layer-2 apply (finalize folded, NREP-replicated sums): fp32 in-place, no ReLU
__global__ __launch_bounds__(256) void bn_apply_f64(float* H, const float* __restrict__ sums,
                                                    const float* __restrict__ gamma,
                                                    const float* __restrict__ beta,
                                                    int N, float invN) {
    __shared__ float ss[128];
    int tid = threadIdx.x;
    if (tid < 64) {
        float su = 0.f, sq = 0.f;
        for (int r = 0; r < NREP; r++) {
            su += sums[r * 128 + tid];
            sq += sums[r * 128 + 64 + tid];
        }
        float mu = su * invN;
        float var = sq * invN - mu * mu;
        float sc = gamma[tid] * rsqrtf(var + EPS_BN);
        ss[tid] = sc;
        ss[64 + tid] = beta[tid] - mu * sc;
    }
    __syncthreads();
    int total4 = N * 16;
    float4* H4 = (float4*)H;
    for (int i = blockIdx.x * 256 + threadIdx.x; i < total4; i += 256 * gridDim.x) {
        int c0 = (i * 4) & 63;
        float4 v = H4[i];
        float4 sc = *(const float4*)&ss[c0];
        float4 sh = *(const float4*)&ss[64 + c0];
        v.x = v.x * sc.x + sh.x;
        v.y = v.y * sc.y + sh.y;
        v.z = v.z * sc.z + sh.z;
        v.w = v.w * sc.w + sh.w;
        H4[i] = v;
    }
}

// ---------------------------------------------------------------- launch
extern "C" void kernel_launch(void* const* d_in, const int* in_sizes, int n_in,
                              void* d_out, int out_size, void* d_ws, size_t ws_size,
                              hipStream_t stream) {
    const float* X = (const float*)d_in[0];
    const int* src = (const int*)d_in[1];
    const int* dst = (const int*)d_in[2];
    const float* Wself1 = (const float*)d_in[3];
    const float* Wneigh1 = (const float*)d_in[4];
    const float* b1 = (const float*)d_in[5];
    const float* g1 = (const float*)d_in[6];
    const float* be1 = (const float*)d_in[7];
    const float* Wself2 = (const float*)d_in[8];
    const float* Wneigh2 = (const float*)d_in[9];
    const float* b2 = (const float*)d_in[10];
    const float* g2 = (const float*)d_in[11];
    const float* be2 = (const float*)d_in[12];
    float* out = (float*)d_out;

    const int N = in_sizes[0] / 128;
    const int E = in_sizes[1];
    const int NB = (N + BINW - 1) >> BINSHIFT;    // 196
    const int NBLK = (E + P_EPB - 1) / P_EPB;     // 196 (<=256 required by p2a)

    char* p = (char*)d_ws;
    auto carve = [&](size_t bytes) {
        char* r = p;
        p += (bytes + 255) & ~(size_t)255;
        return r;
    };
    float* sums1 = (float*)carve((size_t)NREP * 256 * 4);
    float* sums2 = (float*)carve((size_t)NREP * 128 * 4);
    size_t zero_bytes = (size_t)(p - (char*)d_ws);
    int* counts = (int*)carve((size_t)NBLK * NB * 4);
    int* segrel = (int*)carve((size_t)NBLK * NB * 4);
    int* tot = (int*)carve((size_t)NB * 4);
    unsigned* epack = (unsigned*)carve((size_t)E * 4);
    int* csr_src = (int*)carve((size_t)E * 4);
    int* row_start = (int*)carve((size_t)N * 4);
    int* cntg = (int*)carve((size_t)N * 4);
    float* inv_deg = (float*)carve((size_t)N * 4);
    unsigned short* W1f = (unsigned short*)carve(128 * 256 * 2);
    unsigned short* W2f = (unsigned short*)carve(128 * 128 * 2);
    unsigned short* bufS = (unsigned short*)carve((size_t)N * 128 * 2);  // self1 bf16
    signed char* Tq1 = (signed char*)carve((size_t)N * 128);  // neigh1 int8 (128B rows)
    float* scl1 = (float*)carve((size_t)N * 4);               // per-row scales
    signed char* Tq2 = (signed char*)carve((size_t)N * 64);   // neigh2 int8 (64B rows)
    float* scl2 = (float*)carve((size_t)N * 4);
    unsigned short* h1b = (unsigned short*)carve((size_t)N * 128 * 2);   // h1 pre-BN bf16

    hipMemsetAsync(d_ws, 0, zero_bytes, stream);

    const int wB = 192;
    const float invN = 1.0f / (float)N;
    prep_kernel<<<wB + NBLK, 256, 0, stream>>>(Wself1, Wneigh1, Wself2, Wneigh2, W1f, W2f,
                                               dst, counts, E, NB, wB);
    p2a<<<NB, 256, 0, stream>>>(counts, segrel, tot, NB, NBLK);
    p3_scatter<<<NBLK, 512, 0, stream>>>(src, dst, segrel, tot, epack, E, NB);
    p4_csr<<<NB, 512, 0, stream>>>(epack, tot, row_start, cntg, inv_deg, csr_src, N, NB);

    int ggrid = (N + 63) / 64;
    // ---- layer 1 (128 -> 128): fp32 X in (inline cvt), self bf16, neigh int8
    gemm_dual<256, 128, true, false, true><<<ggrid, 256, 0, stream>>>(
        nullptr, X, W1f, nullptr, bufS, Tq1, scl1, N, nullptr, nullptr, nullptr, 0.f);
    agg_row128<<<4096, 256, 0, stream>>>(
        (const unsigned int*)bufS, (const unsigned short*)Tq1, scl1, row_start, cntg,
        inv_deg, csr_src, b1, (unsigned int*)h1b, sums1, N, 16384);

    // ---- layer 2 (128 -> 64): BN1+ReLU fused into A-load; self fp32 -> out
    gemm_dual<128, 64, false, true, false><<<ggrid, 256, 0, stream>>>(
        h1b, nullptr, W2f, out, nullptr, Tq2, scl2, N, sums1, g1, be1, invN);
    agg_row64<<<4096, 256, 0, stream>>>(
        (const unsigned short*)Tq2, scl2, row_start, cntg, inv_deg, csr_src, b2, out,
        sums2, N, 16384);
    bn_apply_f64<<<2048, 256, 0, stream>>>(out, sums2, g2, be2, N, invN);
}